// Round 4
// baseline (270.877 us; speedup 1.0000x reference)
//
#include <hip/hip_runtime.h>

// B=4, T=2048, C=1024, H=16, D=64. fp32 in/out, bf16 internal compute.

typedef unsigned short u16;
typedef unsigned int u32;
typedef __attribute__((ext_vector_type(8))) unsigned short u16x8;
typedef __attribute__((ext_vector_type(4))) unsigned short u16x4;
typedef __attribute__((ext_vector_type(8))) short short8;
typedef __attribute__((ext_vector_type(4))) float f32x4;

__device__ inline u16 f2bf(float f) {
  unsigned u = __float_as_uint(f);
  u = (u + 0x7FFF + ((u >> 16) & 1)) >> 16;  // RNE
  return (u16)u;
}

__device__ inline f32x4 mfma16(short8 a, short8 b, f32x4 c) {
  return __builtin_amdgcn_mfma_f32_16x16x32_bf16(a, b, c, 0, 0, 0);
}

// ---------------- fp32 -> bf16 elementwise convert ----------------
__global__ __launch_bounds__(256) void k_cvt(const float* __restrict__ in,
                                             u16* __restrict__ out) {
  int i = (blockIdx.x * 256 + threadIdx.x) * 4;
  float4 v = *(const float4*)(in + i);
  u16x4 o = {f2bf(v.x), f2bf(v.y), f2bf(v.z), f2bf(v.w)};
  *(u16x4*)(out + i) = o;
}

// ------------- fp32 [R][Cc] -> bf16 transpose [Cc][R] -------------
__global__ __launch_bounds__(256) void k_tw(const float* __restrict__ in,
                                            u16* __restrict__ outT, int R, int Cc) {
  __shared__ u16 t[64][65];
  int c0 = blockIdx.x * 64, r0 = blockIdx.y * 64;
  int a = threadIdx.x & 63, w = threadIdx.x >> 6;
#pragma unroll
  for (int j = 0; j < 16; ++j) {
    int r = w + j * 4;
    t[r][a] = f2bf(in[(size_t)(r0 + r) * Cc + c0 + a]);
  }
  __syncthreads();
#pragma unroll
  for (int j = 0; j < 16; ++j) {
    int c = w + j * 4;
    outT[(size_t)(c0 + c) * R + r0 + a] = t[a][c];
  }
}

// ------- V slice of qkv -> Vt[b][h][d][t]  (bf16 transpose) -------
__global__ __launch_bounds__(256) void k_tv(const u16* __restrict__ qkv,
                                            u16* __restrict__ vt) {
  __shared__ u16 t[64][65];
  int t0 = blockIdx.x * 64, h = blockIdx.y, b = blockIdx.z;
  int a = threadIdx.x & 63, w = threadIdx.x >> 6;
#pragma unroll
  for (int j = 0; j < 16; ++j) {
    int tr = w + j * 4;
    t[tr][a] = qkv[(size_t)(b * 2048 + t0 + tr) * 3072 + 2048 + h * 64 + a];
  }
  __syncthreads();
#pragma unroll
  for (int j = 0; j < 16; ++j) {
    int d = w + j * 4;
    vt[((size_t)((b * 16 + h) * 64 + d)) * 2048 + t0 + a] = t[a][d];
  }
}

// ---- bf16 GEMM: A[M][K] x Bt[N][K] + bias -> bf16 or fp32 out ----
// 128x128 block tile, BK=64, register-staged prefetch (proven structure).
// Block remap (bijective, correctness-independent of XCD mapping):
// XCD-chunk (id = (id0%8)*chunk + id0/8) then 8-wide-m supertile so each
// XCD's concurrent blocks cover an 8m x ny rectangle (neutral in r3 bench;
// kept — harmless and occasionally helps L2).
template <int OUTBF, int QSCALE>
__global__ __launch_bounds__(256) void gemm_bt(const u16* __restrict__ A,
                                               const u16* __restrict__ Bt,
                                               const float* __restrict__ bias,
                                               u16* __restrict__ outb,
                                               float* __restrict__ outf,
                                               int M, int N, int K) {
  __shared__ u16 As[128 * 64];
  __shared__ u16 Bs[128 * 64];
  const int nx = gridDim.x, ny = gridDim.y;
  int id0 = blockIdx.x + blockIdx.y * nx;
  int nwg = nx * ny;
  int q8 = nwg >> 3, x8 = id0 & 7, c8 = id0 >> 3;
  int id = x8 * q8 + c8;                    // nwg % 8 == 0 (bijective)
  int gs = 8 * ny, grp = id / gs, rem = id % gs;  // nx % 8 == 0
  const int m0 = (grp * 8 + (rem & 7)) * 128, n0 = (rem >> 3) * 128;

  const int tid = threadIdx.x, wave = tid >> 6, lane = tid & 63;
  const int quad = lane >> 4, l16 = lane & 15;
  const int wm = (wave & 1) * 64, wn = (wave >> 1) * 64;
  const int lrow = lane >> 3;      // 0..7 within the 8-row slab
  const int lch = lane & 7;        // global 16B chunk within the row
  const int slot = lch ^ lrow;     // swizzled LDS chunk slot
  const u16* sA[4];
  const u16* sB[4];
  int offA[4], offB[4];
#pragma unroll
  for (int j = 0; j < 4; ++j) {
    int r = wave * 32 + j * 8;     // slab base row (multiple of 8)
    sA[j] = A + (size_t)(m0 + r + lrow) * K + lch * 8;
    sB[j] = Bt + (size_t)(n0 + r + lrow) * K + lch * 8;
    offA[j] = (r + lrow) * 64 + slot * 8;
    offB[j] = offA[j];
  }
  // prologue: load tile 0 into regs
  u16x8 ra[4], rb[4];
#pragma unroll
  for (int j = 0; j < 4; ++j) {
    ra[j] = *(const u16x8*)(sA[j]);
    rb[j] = *(const u16x8*)(sB[j]);
  }
  f32x4 acc[4][4] = {};
  for (int kt = 0; kt < K; kt += 64) {
    __syncthreads();  // all waves done reading LDS tile kt-1
#pragma unroll
    for (int j = 0; j < 4; ++j) {
      *(u16x8*)&As[offA[j]] = ra[j];
      *(u16x8*)&Bs[offB[j]] = rb[j];
    }
    __syncthreads();
    if (kt + 64 < K) {  // prefetch tile kt+1 (latency hides under compute)
#pragma unroll
      for (int j = 0; j < 4; ++j) {
        ra[j] = *(const u16x8*)(sA[j] + kt + 64);
        rb[j] = *(const u16x8*)(sB[j] + kt + 64);
      }
    }
    const int sl = l16 & 7;
#pragma unroll
    for (int ks = 0; ks < 2; ++ks) {
      short8 af[4], bf[4];
#pragma unroll
      for (int mt = 0; mt < 4; ++mt)
        af[mt] = *(const short8*)(As + (wm + mt * 16 + l16) * 64 +
                                  ((ks * 4 + quad) ^ sl) * 8);
#pragma unroll
      for (int nt = 0; nt < 4; ++nt)
        bf[nt] = *(const short8*)(Bs + (wn + nt * 16 + l16) * 64 +
                                  ((ks * 4 + quad) ^ sl) * 8);
#pragma unroll
      for (int mt = 0; mt < 4; ++mt)
#pragma unroll
        for (int nt = 0; nt < 4; ++nt)
          acc[mt][nt] = mfma16(af[mt], bf[nt], acc[mt][nt]);
    }
  }
#pragma unroll
  for (int nt = 0; nt < 4; ++nt) {
    int col = n0 + wn + nt * 16 + l16;
    float bv = bias[col];
#pragma unroll
    for (int mt = 0; mt < 4; ++mt) {
      int rowb = m0 + wm + mt * 16 + quad * 4;
#pragma unroll
      for (int r = 0; r < 4; ++r) {
        float v = acc[mt][nt][r] + bv;
        if (QSCALE && col < 1024) v *= 0.18033688f;  // 0.125 * log2(e)
        if (OUTBF)
          outb[(size_t)(rowb + r) * N + col] = f2bf(v);
        else
          outf[(size_t)(rowb + r) * N + col] = v;
      }
    }
  }
}

// ----------------- fused causal flash attention -------------------
// 256-row q-tiles, ONE tile per block: grid (8, H, B) = 512 blocks.
// qb = (b<2)?(7-xx):xx — dispatch-order pairing puts block id i and i+256
// on the same CU with complementary work (sum = 36 k-tiles). Each wave
// owns FOUR 16-row q-groups g=0..3 (rows g*64+wave*16), processed as two
// PAIRS with the byte-level structure of the proven 2-group tile body:
// pair j handles groups gA=2j (dies first at the diagonal) and gB=2j+1
// (guard pattern mA<2 == old g0mode<2; bmask == old g1mask; pair skip via
// continue == old tile skip). Per k-tile the block pays ONE staging+2
// barriers for 68 MFMAs/wave (vs 34 in the 128-row version) and K/V HBM
// traffic halves. Tail tiles c = kt-(nkt-4) in {0..3}: group g full for
// c<g, diagonal for c==g, masked for c>g.
// LDS: P aliases the 256-row Q region (wave-private rows, in-order DS).
#define ATP 72  // LDS row stride (elems): 144B = 9x16B, conflict-light
__global__ __launch_bounds__(256, 2) void attn(const u16* __restrict__ qkv,
                                               const u16* __restrict__ vt,
                                               u16* __restrict__ y) {
  __shared__ u16 shm[384 * ATP];  // 55.3 KB -> 2 blocks/CU
  u16* Qs = shm;                  // 256 rows; aliased as P after frag reads
  u16* Ks = shm + 256 * ATP;      // 64 rows
  u16* Vs = shm + 320 * ATP;      // 64 rows, V^T: [d][t]
  const int xx = blockIdx.x, h = blockIdx.y, b = blockIdx.z;
  const int qb = (b < 2) ? (7 - xx) : xx;
  const int q0 = qb * 256;
  const int nkt = 4 * qb + 4;
  const int tid = threadIdx.x, wave = tid >> 6, lane = tid & 63;
  const int quad = lane >> 4, l16 = lane & 15;
  const u16* Qg = qkv + (size_t)b * 2048 * 3072 + h * 64;
  const u16* Kg = Qg + 1024;
  const u16* Vtg = vt + (size_t)(b * 16 + h) * 64 * 2048;
  const int srow0 = tid >> 3, scol0 = (tid & 7) * 8;  // srow0 in [0,32)
  short8 ones_f;
#pragma unroll
  for (int j = 0; j < 8; ++j) ones_f[j] = 0x3F80;  // bf16 1.0

  // ---- stage Q 256x64 + K/V tile 0 ----
  const u16* kp0 = Kg + (size_t)srow0 * 3072 + scol0;
  const u16* kp1 = kp0 + 32 * 3072;
  const u16* vp0 = Vtg + (size_t)srow0 * 2048 + scol0;
  const u16* vp1 = vp0 + 32 * 2048;
  u16x8 qr[8];
#pragma unroll
  for (int j = 0; j < 8; ++j)
    qr[j] = *(const u16x8*)(Qg + (size_t)(q0 + srow0 + 32 * j) * 3072 + scol0);
  u16x8 kreg0 = *(const u16x8*)kp0, kreg1 = *(const u16x8*)kp1;
  u16x8 vreg0 = *(const u16x8*)vp0, vreg1 = *(const u16x8*)vp1;
#pragma unroll
  for (int j = 0; j < 8; ++j)
    *(u16x8*)&Qs[(size_t)(srow0 + 32 * j) * ATP + scol0] = qr[j];
  *(u16x8*)&Ks[(size_t)srow0 * ATP + scol0] = kreg0;
  *(u16x8*)&Ks[(size_t)(srow0 + 32) * ATP + scol0] = kreg1;
  *(u16x8*)&Vs[(size_t)srow0 * ATP + scol0] = vreg0;
  *(u16x8*)&Vs[(size_t)(srow0 + 32) * ATP + scol0] = vreg1;
  __syncthreads();
  // Q fragments, all four groups (wave reads only its own P-alias rows;
  // same-wave in-order DS: these reads precede any P write by this wave)
  short8 qf[4][2];
#pragma unroll
  for (int g = 0; g < 4; ++g) {
    qf[g][0] = *(const short8*)&Qs[(g * 64 + wave * 16 + l16) * ATP + quad * 8];
    qf[g][1] = *(const short8*)&Qs[(g * 64 + wave * 16 + l16) * ATP + 32 + quad * 8];
  }

  f32x4 lacc[4] = {};
  f32x4 o[4][4] = {};

  for (int kt = 0; kt < nkt; ++kt) {
    if (kt > 0) {
      __syncthreads();  // all waves done reading tile kt-1
      *(u16x8*)&Ks[(size_t)srow0 * ATP + scol0] = kreg0;
      *(u16x8*)&Ks[(size_t)(srow0 + 32) * ATP + scol0] = kreg1;
      *(u16x8*)&Vs[(size_t)srow0 * ATP + scol0] = vreg0;
      *(u16x8*)&Vs[(size_t)(srow0 + 32) * ATP + scol0] = vreg1;
      __syncthreads();
    }
    if (kt + 1 < nkt) {  // prefetch next K/V tile
      kreg0 = *(const u16x8*)(kp0 += 64 * 3072);
      kreg1 = *(const u16x8*)(kp1 += 64 * 3072);
      vreg0 = *(const u16x8*)(vp0 += 64);
      vreg1 = *(const u16x8*)(vp1 += 64);
    }
    const int c = kt - (nkt - 4);  // >=0 only in the 4 tail tiles

#pragma unroll
    for (int j = 0; j < 2; ++j) {
      const int gA = 2 * j, gB = gA + 1;     // compile-time after unroll
      if (c > gB) continue;                  // pair fully masked (block-uniform)
      const int mA = (c < gA) ? 0 : ((c == gA) ? 1 : 2);
      const bool bmask = (c == gB);

      // S^T = K . Q^T for both groups; kf fragments shared
      f32x4 sA[4] = {}, sB[4] = {};
#pragma unroll
      for (int mt = 0; mt < 4; ++mt) {
        short8 kf0 = *(const short8*)&Ks[(mt * 16 + l16) * ATP + quad * 8];
        short8 kf1 = *(const short8*)&Ks[(mt * 16 + l16) * ATP + 32 + quad * 8];
        if (mA < 2) {
          sA[mt] = mfma16(kf0, qf[gA][0], sA[mt]);
          sA[mt] = mfma16(kf1, qf[gA][1], sA[mt]);
        }
        sB[mt] = mfma16(kf0, qf[gB][0], sB[mt]);
        sB[mt] = mfma16(kf1, qf[gB][1], sB[mt]);
      }

      u16* PwA = Qs + (gA * 64 + wave * 16) * ATP;  // wave-private rows
      u16* PwB = Qs + (gB * 64 + wave * 16) * ATP;
      // softmax + P pack, group A
      if (mA < 2) {
        const int qrow = q0 + gA * 64 + wave * 16 + l16;
        const bool masked = (mA == 1);
#pragma unroll
        for (int mt = 0; mt < 4; ++mt) {
          float pe[4];
#pragma unroll
          for (int r = 0; r < 4; ++r) {
            float pv = __builtin_amdgcn_exp2f(sA[mt][r]);
            if (masked) {
              int kcol = kt * 64 + mt * 16 + quad * 4 + r;
              if (kcol > qrow) pv = 0.f;
            }
            pe[r] = pv;
          }
          u32 lo = __builtin_amdgcn_perm(__float_as_uint(pe[1]),
                                         __float_as_uint(pe[0]), 0x07060302u);
          u32 hi = __builtin_amdgcn_perm(__float_as_uint(pe[3]),
                                         __float_as_uint(pe[2]), 0x07060302u);
          uint2 pk = {lo, hi};
          *(uint2*)&PwA[l16 * ATP + mt * 16 + quad * 4] = pk;
        }
      }
      // softmax + P pack, group B (always active when pair not skipped)
      {
        const int qrow = q0 + gB * 64 + wave * 16 + l16;
#pragma unroll
        for (int mt = 0; mt < 4; ++mt) {
          float pe[4];
#pragma unroll
          for (int r = 0; r < 4; ++r) {
            float pv = __builtin_amdgcn_exp2f(sB[mt][r]);
            if (bmask) {
              int kcol = kt * 64 + mt * 16 + quad * 4 + r;
              if (kcol > qrow) pv = 0.f;
            }
            pe[r] = pv;
          }
          u32 lo = __builtin_amdgcn_perm(__float_as_uint(pe[1]),
                                         __float_as_uint(pe[0]), 0x07060302u);
          u32 hi = __builtin_amdgcn_perm(__float_as_uint(pe[3]),
                                         __float_as_uint(pe[2]), 0x07060302u);
          uint2 pk = {lo, hi};
          *(uint2*)&PwB[l16 * ATP + mt * 16 + quad * 4] = pk;
        }
      }

      // O += P.V ; l += P.1 — vf fragments shared between the two groups
#pragma unroll
      for (int ks = 0; ks < 2; ++ks) {
        short8 pfA, pfB;
        if (mA < 2) {
          pfA = *(const short8*)&PwA[l16 * ATP + ks * 32 + quad * 8];
          lacc[gA] = mfma16(pfA, ones_f, lacc[gA]);
        }
        pfB = *(const short8*)&PwB[l16 * ATP + ks * 32 + quad * 8];
        lacc[gB] = mfma16(pfB, ones_f, lacc[gB]);
#pragma unroll
        for (int dt = 0; dt < 4; ++dt) {
          short8 vf = *(const short8*)&Vs[(dt * 16 + l16) * ATP + ks * 32 + quad * 8];
          if (mA < 2) o[gA][dt] = mfma16(pfA, vf, o[gA][dt]);
          o[gB][dt] = mfma16(pfB, vf, o[gB][dt]);
        }
      }
    }
  }

  // epilogue: lacc[g] reg r = l for row quad*4+r — same rows as o[g][dt][r]
#pragma unroll
  for (int g = 0; g < 4; ++g) {
    size_t rb = (size_t)b * 2048 + q0 + g * 64 + wave * 16 + quad * 4;
#pragma unroll
    for (int r = 0; r < 4; ++r) {
      float inv = 1.f / lacc[g][r];
#pragma unroll
      for (int dt = 0; dt < 4; ++dt)
        y[(rb + r) * 1024 + h * 64 + dt * 16 + l16] = f2bf(o[g][dt][r] * inv);
    }
  }
}

extern "C" void kernel_launch(void* const* d_in, const int* in_sizes, int n_in,
                              void* d_out, int out_size, void* d_ws, size_t ws_size,
                              hipStream_t stream) {
  const float* x = (const float*)d_in[0];
  const float* W_attn = (const float*)d_in[1];
  const float* b_attn = (const float*)d_in[2];
  const float* W_proj = (const float*)d_in[3];
  const float* b_proj = (const float*)d_in[4];
  float* out = (float*)d_out;
  char* ws = (char*)d_ws;
  u16* xb  = (u16*)(ws);               // x as bf16 [8192][1024]
  u16* wta = (u16*)(ws + 16777216);    // W_attn^T bf16 [3072][1024]
  u16* wtp = (u16*)(ws + 23068672);    // W_proj^T bf16 [1024][1024]
  u16* qkv = (u16*)(ws + 25165824);    // qkv bf16 [8192][3072] (Q pre-scaled)
  u16* vt  = (u16*)(ws + 75497472);    // V^T bf16 [b][h][64][2048]
  u16* y   = (u16*)(ws + 92274688);    // attn out bf16 [8192][1024]

  k_cvt<<<dim3(8192), 256, 0, stream>>>(x, xb);
  k_tw<<<dim3(48, 16), 256, 0, stream>>>(W_attn, wta, 1024, 3072);
  k_tw<<<dim3(16, 16), 256, 0, stream>>>(W_proj, wtp, 1024, 1024);
  gemm_bt<1, 1><<<dim3(64, 24), 256, 0, stream>>>(xb, wta, b_attn, qkv, nullptr, 8192, 3072, 1024);
  k_tv<<<dim3(32, 16, 4), 256, 0, stream>>>(qkv, vt);
  attn<<<dim3(8, 16, 4), 256, 0, stream>>>(qkv, vt, y);
  gemm_bt<0, 0><<<dim3(64, 8), 256, 0, stream>>>(y, wtp, b_proj, nullptr, out, 8192, 1024, 1024);
}